// Round 3
// baseline (176.263 us; speedup 1.0000x reference)
//
#include <hip/hip_runtime.h>
#include <hip/hip_bf16.h>
#include <stdint.h>

#define NV   65536   // active voxels
#define KOFF 27      // kernel offsets
#define CIN  128
#define COUT 128

typedef __bf16 bf16x8 __attribute__((ext_vector_type(8)));
typedef float  f32x4  __attribute__((ext_vector_type(4)));

__device__ __forceinline__ void async_copy16(void* lds, const void* g) {
    __builtin_amdgcn_global_load_lds(
        (const __attribute__((address_space(1))) void*)g,
        (__attribute__((address_space(3))) void*)lds,
        16, 0, 0);
}

// ---- fused prep kernel (unchanged) --------------------------------------
#define JOB_A_BLOCKS 4097
#define JOB_B_BLOCKS 216    // 27*4*4*2*64 chunks / 256
#define JOB_S_BLOCKS 1728   // 27*65536/4/256

__global__ void k_prep_all(const float* __restrict__ f,
                           uint4* __restrict__ fb4,
                           const float* __restrict__ w,
                           uint4* __restrict__ wfrag4,
                           const int4* __restrict__ in4,
                           const int4* __restrict__ out4,
                           int* __restrict__ nbr) {
    const int b = blockIdx.x;
    const int t = threadIdx.x;
    if (b < JOB_A_BLOCKS) {
        int i = b * 256 + t;
        int total8  = (NV + 1) * CIN / 8;
        int nvalid8 = NV * CIN / 8;
        if (i >= total8) return;
        union { uint4 u; __hip_bfloat16 h[8]; } p;
        if (i < nvalid8) {
            const float4* f4 = (const float4*)f;
            float4 a = f4[i * 2];
            float4 c = f4[i * 2 + 1];
            p.h[0] = __float2bfloat16(a.x);
            p.h[1] = __float2bfloat16(a.y);
            p.h[2] = __float2bfloat16(a.z);
            p.h[3] = __float2bfloat16(a.w);
            p.h[4] = __float2bfloat16(c.x);
            p.h[5] = __float2bfloat16(c.y);
            p.h[6] = __float2bfloat16(c.z);
            p.h[7] = __float2bfloat16(c.w);
        } else {
            p.u = make_uint4(0, 0, 0, 0);
        }
        fb4[i] = p.u;
    } else if (b < JOB_A_BLOCKS + JOB_B_BLOCKS) {
        int c    = (b - JOB_A_BLOCKS) * 256 + t;
        int lane = c & 63;
        int nt   = (c >> 6) & 1;
        int ks   = (c >> 7) & 3;
        int wv   = (c >> 9) & 3;
        int k    = c >> 11;
        int cout = wv * 32 + nt * 16 + (lane & 15);
        int cin0 = ks * 32 + (lane >> 4) * 8;
        const float* wk = w + k * 16384;
        union { uint4 u; __hip_bfloat16 h[8]; } p;
        #pragma unroll
        for (int j = 0; j < 8; ++j)
            p.h[j] = __float2bfloat16(wk[(cin0 + j) * 128 + cout]);
        wfrag4[c] = p.u;
    } else {
        int i = (b - JOB_A_BLOCKS - JOB_B_BLOCKS) * 256 + t;
        int k = i >> 14;
        int4 ii = in4[i];
        int4 oo = out4[i];
        int* nb = nbr + k * (NV + 1);
        nb[oo.x] = ii.x;
        nb[oo.y] = ii.y;
        nb[oo.z] = ii.z;
        nb[oo.w] = ii.w;
    }
}

// ---- main gather-GEMM kernel -------------------------------------------
// Occupancy fix: BM=64 tile (LDS 2x16KB = 32 KB/block) -> 1024 blocks ->
// 4 blocks/CU, 16 waves/CU (was 2 blocks / 8 waves, Occupancy 17%).
// Rounds 0-2 showed the limiter is neither schedule order, nor LDS BW,
// nor HBM: MFMA content is ~2480 cyc/SIMD/offset vs ~5700 measured ->
// latency non-overlap. Four independent barrier domains per CU anti-phase
// so one block's gather/vmcnt stall is hidden by the others' MFMA.
// Wave decomposition = round-1 (proven, VGPR-lean): each wave computes all
// 64 rows x its 32-col slice. acc 32 VGPR, B 2x32 VGPR.
__global__ __launch_bounds__(256, 4)
void sp_conv_main(const __hip_bfloat16* __restrict__ feats,
                  const uint4* __restrict__ wfrag,
                  const int* __restrict__ nbr,
                  const float* __restrict__ bias,
                  float* __restrict__ out) {
    __shared__ unsigned char smem[32768];   // two 16 KB A buffers

    const int t   = threadIdx.x;
    const int bid = blockIdx.x;
    // XCD swizzle: 128 consecutive 64-row tiles per XCD (1024 % 8 == 0)
    const int tile0 = ((bid & 7) * 128 + (bid >> 3)) * 64;

    const int w    = t >> 6;
    const int lane = t & 63;
    const int lr   = lane & 15;
    const int quad = lane >> 4;

    // staging-side XOR map: LDS slot (row = i*16 + t>>4, physchunk = t&15)
    // holds global 16B chunk (t&15) ^ (row&15) -> conflict-free ds_read_b128
    const int srow  = t >> 4;
    const int sbyte = ((t & 15) ^ srow) * 16;

    f32x4 acc[4][2] = {};  // 32 VGPRs

    const unsigned char* featsB = (const unsigned char*)feats;

    int  arows[4];
    uint4 bA[4][2], bB[4][2];   // [ks][nt] fragment regs (role-swapped)

    // ---- helpers (always inlined; rb/ks are call-site literals) ----
    auto AFLOAD = [&](int rb, int ks, bf16x8 (&af)[4]) {
        #pragma unroll
        for (int mt = 0; mt < 4; ++mt)
            af[mt] = *(const bf16x8*)(smem + rb + (mt * 16 + lr) * 256 +
                                      (((ks * 4 + quad) ^ lr) * 16));
    };
    auto MFMA8 = [&](bf16x8 (&af)[4], uint4 (&b)[2]) {
        #pragma unroll
        for (int mt = 0; mt < 4; ++mt)
            #pragma unroll
            for (int nt = 0; nt < 2; ++nt)
                acc[mt][nt] = __builtin_amdgcn_mfma_f32_16x16x32_bf16(
                    af[mt], *(const bf16x8*)&b[nt], acc[mt][nt], 0, 0, 0);
    };
    auto BLOAD = [&](const uint4* wfk, uint4 (&b)[4][2]) {
        #pragma unroll
        for (int ks = 0; ks < 4; ++ks)
            #pragma unroll
            for (int nt = 0; nt < 2; ++nt)
                b[ks][nt] = wfk[ks * 128 + nt * 64];
    };
    auto STAGE = [&](int sb) {
        #pragma unroll
        for (int i = 0; i < 4; ++i) {
            unsigned ar = min((unsigned)arows[i], (unsigned)NV);
            async_copy16(smem + sb + i * 4096 + t * 16,
                         featsB + (size_t)ar * 256 + sbyte);
        }
    };

    // ---- prologue: nbr(0) -> stage A0 -> prefetch nbr(1), B(0) ----
    {
        const int* nbr0 = nbr + tile0;
        #pragma unroll
        for (int i = 0; i < 4; ++i) arows[i] = nbr0[i * 16 + srow];
    }
    STAGE(0);
    __builtin_amdgcn_sched_barrier(0);   // staging ops oldest in vm queue
    {
        const int* nbr1 = nbr + (NV + 1) + tile0;
        #pragma unroll
        for (int i = 0; i < 4; ++i) arows[i] = nbr1[i * 16 + srow];
    }
    BLOAD(wfrag + w * 512 + lane, bA);
    // 12 younger vm ops (4 nbr + 8 B) -> staging A0 guaranteed complete
    asm volatile("s_waitcnt vmcnt(12)" ::: "memory");
    __builtin_amdgcn_s_barrier();
    __builtin_amdgcn_sched_barrier(0);

    // ---- one offset; buse consumed, bload prefilled for k+1 ----
    auto ITER = [&](int k, int rb, uint4 (&buse)[4][2], uint4 (&bload)[4][2]) {
        const int sb = rb ^ 16384;
        // issue A(k+1) staging first (oldest), then nbr(k+2) + B(k+1)
        STAGE(sb);
        __builtin_amdgcn_sched_barrier(0);
        {
            const int* nbrn = nbr + min(k + 2, KOFF - 1) * (NV + 1) + tile0;
            #pragma unroll
            for (int i = 0; i < 4; ++i) arows[i] = nbrn[i * 16 + srow];
        }
        BLOAD(wfrag + (k + 1) * 2048 + w * 512 + lane, bload);
        // compute on buf rb with buse (no VMEM ops in here)
        #pragma unroll
        for (int ks = 0; ks < 4; ++ks) {
            bf16x8 af[4];
            AFLOAD(rb, ks, af);
            __builtin_amdgcn_s_setprio(1);
            MFMA8(af, buse[ks]);
            __builtin_amdgcn_s_setprio(0);
        }
        __builtin_amdgcn_sched_barrier(0);
        // own 4 staging loads complete; 12 nbr/B stay in flight (T4)
        asm volatile("s_waitcnt vmcnt(12)" ::: "memory");
        __builtin_amdgcn_s_barrier();
        __builtin_amdgcn_sched_barrier(0);
    };

    #pragma unroll 1
    for (int kk = 0; kk < KOFF - 1; kk += 2) {
        ITER(kk,     0,     bA, bB);   // even k: read buf0, stage buf1
        ITER(kk + 1, 16384, bB, bA);   // odd  k: read buf1, stage buf0
    }

    // ---- tail k=26: read buf0 with bA; no staging, no barriers ----
    #pragma unroll
    for (int ks = 0; ks < 4; ++ks) {
        bf16x8 af[4];
        AFLOAD(0, ks, af);
        MFMA8(af, bA[ks]);
    }

    // ---- epilogue: C/D layout col = lane&15, row = quad*4 + reg ----
    const int n0w = w * 32;
    float bv[2];
    #pragma unroll
    for (int nt = 0; nt < 2; ++nt) bv[nt] = bias[n0w + nt * 16 + lr];

    #pragma unroll
    for (int mt = 0; mt < 4; ++mt) {
        #pragma unroll
        for (int nt = 0; nt < 2; ++nt) {
            #pragma unroll
            for (int r = 0; r < 4; ++r) {
                int grow = tile0 + mt * 16 + quad * 4 + r;
                out[(size_t)grow * COUT + n0w + nt * 16 + lr] =
                    acc[mt][nt][r] + bv[nt];
            }
        }
    }
}

// ---- launch -------------------------------------------------------------

extern "C" void kernel_launch(void* const* d_in, const int* in_sizes, int n_in,
                              void* d_out, int out_size, void* d_ws, size_t ws_size,
                              hipStream_t stream) {
    const float* features = (const float*)d_in[0];   // [N,128] f32
    const float* weight   = (const float*)d_in[1];   // [27,128,128] f32
    const float* bias     = (const float*)d_in[2];   // [128] f32
    const int*   in_idx   = (const int*)d_in[3];     // [27,N] i32
    const int*   out_idx  = (const int*)d_in[4];     // [27,N] i32
    float* out = (float*)d_out;                      // [N,128] f32

    uint8_t* ws = (uint8_t*)d_ws;
    size_t off = 0;
    __hip_bfloat16* feats_bf = (__hip_bfloat16*)(ws + off);       // (N+1)*128*2
    off += (size_t)(NV + 1) * CIN * 2;
    off = (off + 255) & ~(size_t)255;
    uint4* wfrag = (uint4*)(ws + off);                            // 27*128*128*2 B
    off += (size_t)KOFF * CIN * COUT * 2;
    off = (off + 255) & ~(size_t)255;
    int* nbr = (int*)(ws + off);                                  // 27*(NV+1)*4

    // init nbr to 0xFFFFFFFF (-1 = "no neighbor"; main clamps to zero row)
    hipMemsetAsync(nbr, 0xFF, (size_t)KOFF * (NV + 1) * 4, stream);

    // fused prep: feature cast + weight fragment-permute + rulebook scatter
    k_prep_all<<<JOB_A_BLOCKS + JOB_B_BLOCKS + JOB_S_BLOCKS, 256, 0, stream>>>(
        features, (uint4*)feats_bf, weight, wfrag,
        (const int4*)in_idx, (const int4*)out_idx, nbr);

    // main gather-GEMM: 1024 tiles of 64 rows
    sp_conv_main<<<NV / 64, 256, 0, stream>>>(feats_bf, wfrag, nbr, bias, out);
}

// Round 4
// 151.611 us; speedup vs baseline: 1.1626x; 1.1626x over previous
//
#include <hip/hip_runtime.h>
#include <hip/hip_bf16.h>
#include <stdint.h>

#define NV   65536   // active voxels
#define KOFF 27      // kernel offsets
#define CIN  128
#define COUT 128
#define NSEC (NV + 128)   // nbr_t per-offset stride (16B-aligned, holds dummy slot 65536)

typedef __bf16 bf16x8 __attribute__((ext_vector_type(8)));
typedef float  f32x4  __attribute__((ext_vector_type(4)));

__device__ __forceinline__ void async_copy16(void* lds, const void* g) {
    __builtin_amdgcn_global_load_lds(
        (const __attribute__((address_space(1))) void*)g,
        (__attribute__((address_space(3))) void*)lds,
        16, 0, 0);
}

// ---- fused prep kernel --------------------------------------------------
// Job S now scatters the rulebook into THREAD-ORDER-TRANSPOSED layout:
//   nbr_t[k][tile*128 + s*8 + i] = in-row for out-row (tile*128 + i*16 + s)
// so the main kernel reads its 8 row indices as 2 contiguous int4 loads
// (was 8 scalar loads -> 1/3 of the VMEM instruction stream, the measured
// bottleneck: dur tracks VMEM instr count at ~28 cyc/instr across R0-R3).
#define JOB_A_BLOCKS 4097
#define JOB_B_BLOCKS 216    // 27*4*4*2*64 chunks / 256
#define JOB_S_BLOCKS 1728   // 27*65536/4/256

__global__ void k_prep_all(const float* __restrict__ f,
                           uint4* __restrict__ fb4,
                           const float* __restrict__ w,
                           uint4* __restrict__ wfrag4,
                           const int4* __restrict__ in4,
                           const int4* __restrict__ out4,
                           int* __restrict__ nbr) {
    const int b = blockIdx.x;
    const int t = threadIdx.x;
    if (b < JOB_A_BLOCKS) {
        int i = b * 256 + t;
        int total8  = (NV + 1) * CIN / 8;
        int nvalid8 = NV * CIN / 8;
        if (i >= total8) return;
        union { uint4 u; __hip_bfloat16 h[8]; } p;
        if (i < nvalid8) {
            const float4* f4 = (const float4*)f;
            float4 a = f4[i * 2];
            float4 c = f4[i * 2 + 1];
            p.h[0] = __float2bfloat16(a.x);
            p.h[1] = __float2bfloat16(a.y);
            p.h[2] = __float2bfloat16(a.z);
            p.h[3] = __float2bfloat16(a.w);
            p.h[4] = __float2bfloat16(c.x);
            p.h[5] = __float2bfloat16(c.y);
            p.h[6] = __float2bfloat16(c.z);
            p.h[7] = __float2bfloat16(c.w);
        } else {
            p.u = make_uint4(0, 0, 0, 0);
        }
        fb4[i] = p.u;
    } else if (b < JOB_A_BLOCKS + JOB_B_BLOCKS) {
        int c    = (b - JOB_A_BLOCKS) * 256 + t;
        int lane = c & 63;
        int nt   = (c >> 6) & 1;
        int ks   = (c >> 7) & 3;
        int wv   = (c >> 9) & 3;
        int k    = c >> 11;
        int cout = wv * 32 + nt * 16 + (lane & 15);
        int cin0 = ks * 32 + (lane >> 4) * 8;
        const float* wk = w + k * 16384;
        union { uint4 u; __hip_bfloat16 h[8]; } p;
        #pragma unroll
        for (int j = 0; j < 8; ++j)
            p.h[j] = __float2bfloat16(wk[(cin0 + j) * 128 + cout]);
        wfrag4[c] = p.u;
    } else {
        int i = (b - JOB_A_BLOCKS - JOB_B_BLOCKS) * 256 + t;
        int k = i >> 14;
        int4 ii = in4[i];
        int4 oo = out4[i];
        int* nb = nbr + (size_t)k * NSEC;
        // transposed position: tile*128 + (o&15)*8 + ((o>>4)&7)
        // (bijective on low 7 bits; dummy o=65536 -> pos 65536 < NSEC-aligned alloc)
        auto POS = [](int o) {
            return (o >> 7) * 128 + (o & 15) * 8 + ((o >> 4) & 7);
        };
        nb[POS(oo.x)] = ii.x;
        nb[POS(oo.y)] = ii.y;
        nb[POS(oo.z)] = ii.z;
        nb[POS(oo.w)] = ii.w;
    }
}

// ---- main gather-GEMM kernel -------------------------------------------
// R1-proven config (BM=128, 2 blocks/CU, wave = 128 rows x 32 cols, LDS
// double-buffer, counted vmcnt) with the nbr loads collapsed 8 scalar ->
// 2 x int4 via the transposed rulebook. VMEM wave-instrs per CU per offset:
// 192 -> 144 (the measured limiter: ~28 cyc per VMEM instruction).
__global__ __launch_bounds__(256, 2)
void sp_conv_main(const __hip_bfloat16* __restrict__ feats,
                  const uint4* __restrict__ wfrag,
                  const int* __restrict__ nbrt,
                  const float* __restrict__ bias,
                  float* __restrict__ out) {
    __shared__ unsigned char smem[65536];   // two 32 KB A buffers

    const int t   = threadIdx.x;
    const int bid = blockIdx.x;
    // XCD swizzle: consecutive 64-tile ranges per XCD (512 % 8 == 0, bijective)
    const int tile0 = ((bid & 7) * 64 + (bid >> 3)) * 128;

    const int w    = t >> 6;
    const int lane = t & 63;
    const int lr   = lane & 15;
    const int quad = lane >> 4;

    // staging-side XOR map: LDS slot (row = i*16 + srow, physchunk = t&15)
    // holds global 16B chunk (t&15) ^ (row&15) -> conflict-free ds_read_b128
    const int srow  = t >> 4;
    const int sbyte = ((t & 15) ^ srow) * 16;

    f32x4 acc[8][2] = {};  // 64 VGPRs

    const unsigned char* featsB = (const unsigned char*)feats;

    int  arows[8];
    uint4 bA[4][2], bB[4][2];   // [ks][nt] fragment regs (role-swapped)

    // ---- helpers (always inlined; rb/ks are call-site literals) ----
    auto NLOAD = [&](int k) {   // 2 x int4: rows i*16+srow, i=0..7
        const int4* np = (const int4*)(nbrt + (size_t)k * NSEC + tile0 + srow * 8);
        int4 a0 = np[0];
        int4 a1 = np[1];
        arows[0] = a0.x; arows[1] = a0.y; arows[2] = a0.z; arows[3] = a0.w;
        arows[4] = a1.x; arows[5] = a1.y; arows[6] = a1.z; arows[7] = a1.w;
    };
    auto STAGE = [&](int sb) {
        #pragma unroll
        for (int i = 0; i < 8; ++i) {
            unsigned ar = min((unsigned)arows[i], (unsigned)NV);
            async_copy16(smem + sb + i * 4096 + t * 16,
                         featsB + (size_t)ar * 256 + sbyte);
        }
    };
    auto BLOAD = [&](const uint4* wfk, uint4 (&b)[4][2]) {
        #pragma unroll
        for (int ks = 0; ks < 4; ++ks)
            #pragma unroll
            for (int nt = 0; nt < 2; ++nt)
                b[ks][nt] = wfk[ks * 128 + nt * 64];
    };
    auto AFLOAD = [&](int rb, int ks, bf16x8 (&af)[8]) {
        #pragma unroll
        for (int mt = 0; mt < 8; ++mt)
            af[mt] = *(const bf16x8*)(smem + rb + (mt * 16 + lr) * 256 +
                                      (((ks * 4 + quad) ^ lr) * 16));
    };
    auto MFMA16 = [&](bf16x8 (&af)[8], uint4 (&b)[2]) {
        #pragma unroll
        for (int mt = 0; mt < 8; ++mt)
            #pragma unroll
            for (int nt = 0; nt < 2; ++nt)
                acc[mt][nt] = __builtin_amdgcn_mfma_f32_16x16x32_bf16(
                    af[mt], *(const bf16x8*)&b[nt], acc[mt][nt], 0, 0, 0);
    };

    // ---- prologue: nbr(0) -> stage A0 -> prefetch nbr(1), B(0) ----
    NLOAD(0);
    STAGE(0);
    __builtin_amdgcn_sched_barrier(0);   // staging ops oldest in vm queue
    NLOAD(1);
    BLOAD(wfrag + w * 512 + lane, bA);
    // 10 younger vm ops (2 nbr + 8 B) -> staging A0 (+nbr0) complete
    asm volatile("s_waitcnt vmcnt(10)" ::: "memory");
    __builtin_amdgcn_s_barrier();
    __builtin_amdgcn_sched_barrier(0);

    // ---- one offset; buse consumed, bload prefilled for k+1 ----
    auto ITER = [&](int k, int rb, uint4 (&buse)[4][2], uint4 (&bload)[4][2]) {
        // issue A(k+1) staging first (oldest), then nbr(k+2) + B(k+1)
        STAGE(rb ^ 32768);
        __builtin_amdgcn_sched_barrier(0);
        NLOAD(min(k + 2, KOFF - 1));   // dup at k=25 harmless
        BLOAD(wfrag + (k + 1) * 2048 + w * 512 + lane, bload);
        // compute on buf rb with buse (no VMEM ops in here)
        #pragma unroll
        for (int ks = 0; ks < 4; ++ks) {
            bf16x8 af[8];
            AFLOAD(rb, ks, af);
            __builtin_amdgcn_s_setprio(1);
            MFMA16(af, buse[ks]);
            __builtin_amdgcn_s_setprio(0);
        }
        __builtin_amdgcn_sched_barrier(0);
        // own 8 staging loads complete; 10 nbr/B stay in flight (T4)
        asm volatile("s_waitcnt vmcnt(10)" ::: "memory");
        __builtin_amdgcn_s_barrier();
        __builtin_amdgcn_sched_barrier(0);
    };

    #pragma unroll 1
    for (int kk = 0; kk < KOFF - 1; kk += 2) {
        ITER(kk,     0,     bA, bB);   // even k: read buf0, stage buf1
        ITER(kk + 1, 32768, bB, bA);   // odd  k: read buf1, stage buf0
    }

    // ---- tail k=26: read buf0 with bA; no staging, no barriers ----
    #pragma unroll
    for (int ks = 0; ks < 4; ++ks) {
        bf16x8 af[8];
        AFLOAD(0, ks, af);
        MFMA16(af, bA[ks]);
    }

    // ---- epilogue: C/D layout col = lane&15, row = quad*4 + reg ----
    const int n0w = w * 32;
    float bv[2];
    #pragma unroll
    for (int nt = 0; nt < 2; ++nt) bv[nt] = bias[n0w + nt * 16 + lr];

    #pragma unroll
    for (int mt = 0; mt < 8; ++mt) {
        #pragma unroll
        for (int nt = 0; nt < 2; ++nt) {
            #pragma unroll
            for (int r = 0; r < 4; ++r) {
                int grow = tile0 + mt * 16 + quad * 4 + r;
                out[(size_t)grow * COUT + n0w + nt * 16 + lr] =
                    acc[mt][nt][r] + bv[nt];
            }
        }
    }
}

// ---- launch -------------------------------------------------------------

extern "C" void kernel_launch(void* const* d_in, const int* in_sizes, int n_in,
                              void* d_out, int out_size, void* d_ws, size_t ws_size,
                              hipStream_t stream) {
    const float* features = (const float*)d_in[0];   // [N,128] f32
    const float* weight   = (const float*)d_in[1];   // [27,128,128] f32
    const float* bias     = (const float*)d_in[2];   // [128] f32
    const int*   in_idx   = (const int*)d_in[3];     // [27,N] i32
    const int*   out_idx  = (const int*)d_in[4];     // [27,N] i32
    float* out = (float*)d_out;                      // [N,128] f32

    uint8_t* ws = (uint8_t*)d_ws;
    size_t off = 0;
    __hip_bfloat16* feats_bf = (__hip_bfloat16*)(ws + off);       // (N+1)*128*2
    off += (size_t)(NV + 1) * CIN * 2;
    off = (off + 255) & ~(size_t)255;
    uint4* wfrag = (uint4*)(ws + off);                            // 27*128*128*2 B
    off += (size_t)KOFF * CIN * COUT * 2;
    off = (off + 255) & ~(size_t)255;
    int* nbr = (int*)(ws + off);                                  // 27*NSEC*4 (transposed)

    // init nbr_t to 0xFFFFFFFF (-1 = "no neighbor"; main clamps to zero row)
    hipMemsetAsync(nbr, 0xFF, (size_t)KOFF * NSEC * 4, stream);

    // fused prep: feature cast + weight fragment-permute + rulebook scatter
    k_prep_all<<<JOB_A_BLOCKS + JOB_B_BLOCKS + JOB_S_BLOCKS, 256, 0, stream>>>(
        features, (uint4*)feats_bf, weight, wfrag,
        (const int4*)in_idx, (const int4*)out_idx, nbr);

    // main gather-GEMM: 512 tiles of 128 rows
    sp_conv_main<<<NV / 128, 256, 0, stream>>>(feats_bf, wfrag, nbr, bias, out);
}